// Round 9
// baseline (241.739 us; speedup 1.0000x reference)
//
#include <hip/hip_runtime.h>
#include <math.h>

// Problem constants
constexpr int Bc = 2;
constexpr int Sc = 2048;
constexpr int Dc = 1024;
constexpr int Hc = 16;
constexpr int HDc = 64;

// Q pre-scale: attention 1/sqrt(64) folded with log2(e) for exp2-domain softmax
constexpr float QSC = 0.125f * 1.4426950408889634f;

typedef __attribute__((ext_vector_type(8))) short bf16x8;
typedef __attribute__((ext_vector_type(4))) float f32x4;
typedef __attribute__((ext_vector_type(4))) unsigned short us4;
typedef __attribute__((ext_vector_type(2))) unsigned int u32x2;
typedef __attribute__((ext_vector_type(4))) unsigned int u32x4;

typedef const __attribute__((address_space(1))) unsigned int* gp_t;
typedef __attribute__((address_space(3))) unsigned int* lp_t;

// fp32 -> bf16 round-to-nearest-even (returns low 16 bits)
__device__ __forceinline__ unsigned f2bf(float x) {
    unsigned u = __float_as_uint(x);
    return (u + 0x7FFFu + ((u >> 16) & 1u)) >> 16;
}

__device__ __forceinline__ void split2(float x, unsigned short& h, unsigned short& l) {
    unsigned hh = f2bf(x);
    h = (unsigned short)hh;
    l = (unsigned short)f2bf(x - __uint_as_float(hh << 16));
}

// gfx950 cross-lane half-swaps: a=vdst, b=src; both updated.
#if __has_builtin(__builtin_amdgcn_permlane32_swap)
__device__ __forceinline__ void plswap32(unsigned& a, unsigned& b) {
    u32x2 r = __builtin_amdgcn_permlane32_swap(a, b, false, false);
    a = r.x; b = r.y;
}
#else
__device__ __forceinline__ void plswap32(unsigned& a, unsigned& b) {
    asm volatile("v_permlane32_swap_b32 %0, %1" : "+v"(a), "+v"(b));
}
#endif
#if __has_builtin(__builtin_amdgcn_permlane16_swap)
__device__ __forceinline__ void plswap16(unsigned& a, unsigned& b) {
    u32x2 r = __builtin_amdgcn_permlane16_swap(a, b, false, false);
    a = r.x; b = r.y;
}
#else
__device__ __forceinline__ void plswap16(unsigned& a, unsigned& b) {
    asm volatile("v_permlane16_swap_b32 %0, %1" : "+v"(a), "+v"(b));
}
#endif

// exp2 of 4 S-values, packed (truncating) into two bf16-pair words:
// w0 = {bf16(s0) lo, bf16(s1) hi}, w1 = {bf16(s2) lo, bf16(s3) hi}
__device__ __forceinline__ void exppack(const f32x4& sv, unsigned& w0, unsigned& w1) {
    unsigned u0 = __float_as_uint(__builtin_amdgcn_exp2f(sv[0]));
    unsigned u1 = __float_as_uint(__builtin_amdgcn_exp2f(sv[1]));
    unsigned u2 = __float_as_uint(__builtin_amdgcn_exp2f(sv[2]));
    unsigned u3 = __float_as_uint(__builtin_amdgcn_exp2f(sv[3]));
    w0 = __builtin_amdgcn_perm(u1, u0, 0x07060302u);
    w1 = __builtin_amdgcn_perm(u3, u2, 0x07060302u);
}

// ---------------------------------------------------------------------------
// RoPE cos/sin table: [S][32] each, double precision angles.
// ---------------------------------------------------------------------------
__global__ void rope_table(float* __restrict__ ct, float* __restrict__ st_) {
    int id = blockIdx.x * 256 + threadIdx.x;
    int s = id >> 5;
    int i = id & 31;
    double invf = pow(10000.0, -(double)i / 32.0);
    double ang = (double)s * invf;
    ct[id] = (float)cos(ang);
    st_[id] = (float)sin(ang);
}

// ---------------------------------------------------------------------------
// Convert: x -> bf16 hi; Wq/Wk/Wv -> hi; Wo -> hi + lo.
// ---------------------------------------------------------------------------
__global__ void split_xw(const float* __restrict__ x,
                         const float* __restrict__ Wq, const float* __restrict__ Wk,
                         const float* __restrict__ Wv, const float* __restrict__ Wo,
                         unsigned short* __restrict__ xh,
                         unsigned short* __restrict__ whAll, unsigned short* __restrict__ wlAll) {
    int y = blockIdx.y;
    const float* src;
    unsigned short* h;
    unsigned short* l = nullptr;
    int n;
    if (y == 0) { src = x; h = xh; n = 1 << 22; }
    else {
        src = (y == 1) ? Wq : (y == 2) ? Wk : (y == 3) ? Wv : Wo;
        h = whAll + (size_t)(y - 1) * (1 << 20);
        if (y == 4) l = wlAll + (size_t)3 * (1 << 20);
        n = 1 << 20;
    }
    int i = (blockIdx.x * 256 + threadIdx.x) * 4;
    if (i >= n) return;
    float4 v = *(const float4*)(src + i);
    us4 hh;
    ((unsigned short*)&hh)[0] = (unsigned short)f2bf(v.x);
    ((unsigned short*)&hh)[1] = (unsigned short)f2bf(v.y);
    ((unsigned short*)&hh)[2] = (unsigned short)f2bf(v.z);
    ((unsigned short*)&hh)[3] = (unsigned short)f2bf(v.w);
    *(us4*)(h + i) = hh;
    if (l) {
        us4 ll;
        const float* vp = (const float*)&v;
#pragma unroll
        for (int e = 0; e < 4; e++) {
            unsigned short hi = ((unsigned short*)&hh)[e];
            ((unsigned short*)&ll)[e] =
                (unsigned short)f2bf(vp[e] - __uint_as_float((unsigned)hi << 16));
        }
        *(us4*)(l + i) = ll;
    }
}

// ---------------------------------------------------------------------------
// QKV GEMM v8: 256x256 tile, BK=64, 8-PHASE schedule (T3+T4+T5).
// 8 waves (512 thr), per-wave 128x64 output (wr=wave>>2, wc=wave&3).
// LDS 128 KB: As/Bs[2 buf][8 kcell][256 row][8 short], conflict-free cells.
// Per phase: stage 1 K-half (2 gloads) -> vmcnt(10) odd phases -> barrier ->
// ds_reads -> 16 MFMA @setprio(1) -> barrier. Loads stream 4-7 phases ahead;
// the DMA queue NEVER drains in the main loop (peeled last iter: 10/8/4/0).
// Epilogues: z=0 Q (RoPE+QSC), z=1 K cells, z=2 V^T cells (same formulas,
// i extended to 8, ii=i&3, hcol=by*4+wc).
// ---------------------------------------------------------------------------
__global__ __launch_bounds__(512, 2) void gemm_qkv8(
    const unsigned short* __restrict__ Ah,
    const unsigned short* __restrict__ whAll,
    unsigned short* __restrict__ Qh,
    unsigned short* __restrict__ Kh,
    unsigned short* __restrict__ Vh,
    const float* __restrict__ ct, const float* __restrict__ st_) {
    constexpr int K = 1024;
    __shared__ __align__(16) unsigned short As[2][16384], Bs[2][16384];

    const int t = threadIdx.x;
    const int lane = t & 63;
    const int wave = t >> 6;               // 0..7
    const int l15 = lane & 15;
    const int quad = lane >> 4;
    const int wr = wave >> 2;              // 0..1: 128-row strip
    const int wc = wave & 3;               // 0..3: 64-col strip (= head)
    const int m0 = blockIdx.x * 256;
    const int n0 = blockIdx.y * 256;
    const int z = blockIdx.z;
    const unsigned short* Wh = whAll + (size_t)z * (1 << 20);

    // staging map: wave w, load q: kcell_rel = (2w+q)>>2, rows ((2w+q)&3)*64+lane
    const int kcr0 = (2 * wave + 0) >> 2, rb0 = ((2 * wave + 0) & 3) * 64;
    const int kcr1 = (2 * wave + 1) >> 2, rb1 = ((2 * wave + 1) & 3) * 64;
    const unsigned short* gA0 = Ah + (size_t)(m0 + rb0 + lane) * K + kcr0 * 8;
    const unsigned short* gA1 = Ah + (size_t)(m0 + rb1 + lane) * K + kcr1 * 8;
    const unsigned short* gB0 = Wh + (size_t)(n0 + rb0 + lane) * K + kcr0 * 8;
    const unsigned short* gB1 = Wh + (size_t)(n0 + rb1 + lane) * K + kcr1 * 8;
    const int ld0 = (kcr0 * 256 + rb0 + lane) * 8;   // shorts; + kh*8192
    const int ld1 = (kcr1 * 256 + rb1 + lane) * 8;

    f32x4 acc[8][4];
#pragma unroll
    for (int i = 0; i < 8; i++)
#pragma unroll
        for (int j = 0; j < 4; j++) acc[i][j] = (f32x4){0.f, 0.f, 0.f, 0.f};
    bf16x8 af[8];

// stage one K-half (kh) of tile X for tensor with bases (g0,g1) into LARR
#define STG(g0, g1, LARR, X, KH) do {                                                      \
        const int _ko = (X) * 64 + (KH) * 32;                                              \
        const int _lo = (KH) * 8192;                                                       \
        __builtin_amdgcn_global_load_lds((gp_t)((g0) + _ko),                               \
            (lp_t)(&LARR[(X) & 1][ld0 + _lo]), 16, 0, 0);                                  \
        __builtin_amdgcn_global_load_lds((gp_t)((g1) + _ko),                               \
            (lp_t)(&LARR[(X) & 1][ld1 + _lo]), 16, 0, 0);                                  \
    } while (0)

#define VM10 asm volatile("s_waitcnt vmcnt(10)" ::: "memory")
#define VM8  asm volatile("s_waitcnt vmcnt(8)" ::: "memory")
#define VM4  asm volatile("s_waitcnt vmcnt(4)" ::: "memory")
#define VM0  asm volatile("s_waitcnt vmcnt(0)" ::: "memory")

// one phase: PRE (stage [+vmcnt]) -> barrier -> reads -> MFMA -> barrier
#define CPH(BUF, KS, J0, RA, PRE) do {                                                     \
        PRE;                                                                               \
        asm volatile("s_barrier" ::: "memory");                                            \
        const unsigned short* _a = &As[(BUF)][0];                                          \
        const unsigned short* _b = &Bs[(BUF)][0];                                          \
        if (RA) {                                                                          \
            _Pragma("unroll")                                                              \
            for (int _i = 0; _i < 8; _i++)                                                 \
                af[_i] = *(const bf16x8*)&_a[((KS) * 4 + quad) * 2048 +                    \
                                             (wr * 128 + _i * 16 + l15) * 8];              \
        }                                                                                  \
        bf16x8 _bf0 = *(const bf16x8*)&_b[((KS) * 4 + quad) * 2048 +                       \
                                          (wc * 64 + (J0) * 16 + l15) * 8];                \
        bf16x8 _bf1 = *(const bf16x8*)&_b[((KS) * 4 + quad) * 2048 +                       \
                                          (wc * 64 + ((J0) + 1) * 16 + l15) * 8];          \
        __builtin_amdgcn_s_setprio(1);                                                     \
        _Pragma("unroll")                                                                  \
        for (int _i = 0; _i < 8; _i++) {                                                   \
            acc[_i][(J0)]     = __builtin_amdgcn_mfma_f32_16x16x32_bf16(af[_i], _bf0,      \
                                    acc[_i][(J0)], 0, 0, 0);                               \
            acc[_i][(J0) + 1] = __builtin_amdgcn_mfma_f32_16x16x32_bf16(af[_i], _bf1,      \
                                    acc[_i][(J0) + 1], 0, 0, 0);                           \
        }                                                                                  \
        __builtin_amdgcn_s_setprio(0);                                                     \
        asm volatile("s_barrier" ::: "memory");                                            \
    } while (0)

    // prologue: T0 all 4 halves + T1 k0-halves (12 loads/thread)
    STG(gA0, gA1, As, 0, 0); STG(gB0, gB1, Bs, 0, 0);
    STG(gA0, gA1, As, 0, 1); STG(gB0, gB1, Bs, 0, 1);
    STG(gA0, gA1, As, 1, 0); STG(gB0, gB1, Bs, 1, 0);

    // main loop: 7 full iterations (tiles 0..13), stages reference tiles+2,+3
    for (int e = 0; e < 14; e += 2) {
        CPH(0, 0, 0, 1, STG(gA0, gA1, As, e + 1, 1); VM10);   // P1: tileE ks0 j01
        CPH(0, 0, 2, 0, STG(gB0, gB1, Bs, e + 1, 1));          // P2: tileE ks0 j23
        CPH(0, 1, 0, 1, STG(gA0, gA1, As, e + 2, 0); VM10);   // P3: tileE ks1 j01
        CPH(0, 1, 2, 0, STG(gB0, gB1, Bs, e + 2, 0));          // P4: tileE ks1 j23
        CPH(1, 0, 0, 1, STG(gA0, gA1, As, e + 2, 1); VM10);   // P5: tileO ks0 j01
        CPH(1, 0, 2, 0, STG(gB0, gB1, Bs, e + 2, 1));          // P6: tileO ks0 j23
        CPH(1, 1, 0, 1, STG(gA0, gA1, As, e + 3, 0); VM10);   // P7: tileO ks1 j01
        CPH(1, 1, 2, 0, STG(gB0, gB1, Bs, e + 3, 0));          // P8: tileO ks1 j23
    }
    // peeled last iteration (tiles 14, 15): only tile-15 k1-halves left to stage
    CPH(0, 0, 0, 1, STG(gA0, gA1, As, 15, 1); VM10);
    CPH(0, 0, 2, 0, STG(gB0, gB1, Bs, 15, 1));
    CPH(0, 1, 0, 1, VM8);
    CPH(0, 1, 2, 0, );
    CPH(1, 0, 0, 1, VM4);
    CPH(1, 0, 2, 0, );
    CPH(1, 1, 0, 1, VM0);
    CPH(1, 1, 2, 0, );

#undef CPH
#undef STG
#undef VM10
#undef VM8
#undef VM4
#undef VM0

    // ---- fused epilogue (per-wave 128x64 at (wr, wc)) ----
    const int hcol = blockIdx.y * 4 + wc;   // head index 0..15
    if (z == 2) {
        // V^T cells, K=32 A-operand layout: ii = i&3
#pragma unroll
        for (int i = 0; i < 8; i++) {
            int m_base = m0 + wr * 128 + i * 16 + quad * 4;
            int bbk = m_base >> 11;
            int T = (m_base & (Sc - 1)) >> 6;
            int ii = i & 3;
            int kk = ii >> 1;
            int qd = ((ii & 1) << 1) | (quad >> 1);
            int tj = (quad & 1) * 4;
            size_t tilebase = (((size_t)(bbk * Hc + hcol)) * 32 + T) * 4096;
#pragma unroll
            for (int jj = 0; jj < 4; jj++) {
                int d = jj * 16 + l15;
                size_t off = tilebase + (size_t)(((kk * 4 + qd) * 64 + d) * 8 + tj);
                us4 v4;
#pragma unroll
                for (int r = 0; r < 4; r++)
                    ((unsigned short*)&v4)[r] = (unsigned short)f2bf(acc[i][jj][r]);
                *(us4*)(Vh + off) = v4;
            }
        }
    } else {
#pragma unroll
        for (int i = 0; i < 8; i++)
#pragma unroll
            for (int r = 0; r < 4; r++) {
                int m = m0 + wr * 128 + i * 16 + quad * 4 + r;
                int bbk = m >> 11, s = m & (Sc - 1);
#pragma unroll
                for (int jp = 0; jp < 2; jp++) {
                    int d = jp * 16 + l15;                     // 0..31
                    float cs = ct[s * 32 + d];
                    float sn = st_[s * 32 + d];
                    float x0 = acc[i][jp][r];
                    float x1 = acc[i][jp + 2][r];
                    float y0 = x0 * cs - x1 * sn;
                    float y1 = x1 * cs + x0 * sn;
                    if (z == 0) {
                        size_t rowb = (((size_t)(bbk * Hc + hcol)) * Sc + s) * HDc;
                        Qh[rowb + d]      = (unsigned short)f2bf(y0 * QSC);
                        Qh[rowb + d + 32] = (unsigned short)f2bf(y1 * QSC);
                    } else {
                        int T = s >> 6, tok = s & 63;
                        size_t tb = (((size_t)(bbk * Hc + hcol)) * 32 + T) * 8;
                        size_t off0 = ((tb + (d >> 3)) * 64 + tok) * 8 + (d & 7);
                        size_t off1 = ((tb + (d >> 3) + 4) * 64 + tok) * 8 + (d & 7);
                        Kh[off0] = (unsigned short)f2bf(y0);
                        Kh[off1] = (unsigned short)f2bf(y1);
                    }
                }
            }
    }
}

// ---------------------------------------------------------------------------
// MFMA flash attention v10: all-K=32 MFMA, 256 q/block (8 waves x 2 bands),
// grid 256 = 1 block/CU. Triple-buffered K/V + per-wave counted vmcnt(2)
// before raw s_barrier. UNTOUCHED (round-7 proven, <61us).
// ---------------------------------------------------------------------------
__global__ __launch_bounds__(512) void attn10(
    const unsigned short* __restrict__ Qh,
    const unsigned short* __restrict__ Kh,
    const unsigned short* __restrict__ Vh,
    unsigned short* __restrict__ AOh, unsigned short* __restrict__ AOl) {
    __shared__ __align__(16) unsigned short KsH[3 * 4096], VtH[3 * 4096];

    const int t = threadIdx.x;
    const int lane = t & 63;
    const int wave = t >> 6;               // 0..7
    const int l = lane & 15;
    const int quad = lane >> 4;
    const int id = blockIdx.x;             // 0..255
    const int bh = (id & 7) * 4 + (id >> 6);   // XCD-clustered (4 bh / XCD slot)
    const int qt = (id >> 3) & 7;
    const int q0 = qt * 256;
    const int b = bh >> 4;
    const int hh = bh & 15;

    const bf16x8 ONES8 = {(short)0x3F80, (short)0x3F80, (short)0x3F80, (short)0x3F80,
                          (short)0x3F80, (short)0x3F80, (short)0x3F80, (short)0x3F80};

    // Q fragments (B operand: n=q=lane&15, k=d=quad*8+j); band bnd -> rows
    // q0 + wave*32 + bnd*16 + l
    bf16x8 qf[2][2];
#pragma unroll
    for (int bnd = 0; bnd < 2; bnd++) {
        size_t rowb = ((size_t)bh * Sc + q0 + wave * 32 + bnd * 16 + l) * HDc;
#pragma unroll
        for (int ks = 0; ks < 2; ks++)
            qf[bnd][ks] = *(const bf16x8*)(Qh + rowb + ks * 32 + quad * 8);
    }

    f32x4 o[2][4], lac[2];
#pragma unroll
    for (int bnd = 0; bnd < 2; bnd++) {
        lac[bnd] = (f32x4){0.f, 0.f, 0.f, 0.f};
#pragma unroll
        for (int i = 0; i < 4; i++) o[bnd][i] = (f32x4){0.f, 0.f, 0.f, 0.f};
    }

    // staging: 16 chunks of 512 elems per kt (K: 0-7, V: 8-15); wave w owns
    // chunks w*2, w*2+1 (waves 0-3 -> K, waves 4-7 -> V). LDS dst uniform.
    const int tensor = wave >> 2;          // 0 = K, 1 = V
    const int coff0 = (wave * 2) & 7;      // 0,2,4,6
    unsigned short* larr = tensor ? VtH : KsH;
    const unsigned short* gT =
        (tensor ? Vh : Kh) + (size_t)bh * Sc * HDc + coff0 * 512 + lane * 8;

    // prologue: kt=0 into buffer 0
#pragma unroll
    for (int q = 0; q < 2; q++)
        __builtin_amdgcn_global_load_lds(
            (gp_t)(gT + q * 512),
            (lp_t)(larr + coff0 * 512 + q * 512),
            16, 0, 0);

    int bc = 0;   // kt % 3
    for (int kt = 0; kt < 32; kt++) {
        if (kt + 1 < 32) {
            int nb = bc + 1; if (nb == 3) nb = 0;     // (kt+1) % 3
            const unsigned short* g = gT + (size_t)(kt + 1) * 4096;
            unsigned short* dst = larr + nb * 4096 + coff0 * 512;
#pragma unroll
            for (int q = 0; q < 2; q++)
                __builtin_amdgcn_global_load_lds(
                    (gp_t)(g + q * 512),
                    (lp_t)(dst + q * 512),
                    16, 0, 0);
            asm volatile("s_waitcnt vmcnt(2)" ::: "memory");   // own kt-loads landed
        } else {
            asm volatile("s_waitcnt vmcnt(0)" ::: "memory");
        }
        __builtin_amdgcn_s_barrier();                          // all waves' kt-loads landed
        const unsigned short* Kbuf = KsH + bc * 4096;
        const unsigned short* Vbuf = VtH + bc * 4096;

        // ---- S^T = K @ Q^T: A=K frag (m=tok), B=Q frag (n=q) ----
        f32x4 s[2][4];
#pragma unroll
        for (int bnd = 0; bnd < 2; bnd++)
#pragma unroll
            for (int tt = 0; tt < 4; tt++) s[bnd][tt] = (f32x4){0.f, 0.f, 0.f, 0.f};
        __builtin_amdgcn_s_setprio(1);
#pragma unroll
        for (int ks = 0; ks < 2; ks++)
#pragma unroll
            for (int tt = 0; tt < 4; tt++) {
                bf16x8 kf = *(const bf16x8*)&Kbuf[((ks * 4 + quad) * 64 + tt * 16 + l) * 8];
                s[0][tt] = __builtin_amdgcn_mfma_f32_16x16x32_bf16(kf, qf[0][ks], s[0][tt], 0, 0, 0);
                s[1][tt] = __builtin_amdgcn_mfma_f32_16x16x32_bf16(kf, qf[1][ks], s[1][tt], 0, 0, 0);
            }
        __builtin_amdgcn_s_setprio(0);

        // ---- P^T = exp2(S^T), packed + permlane-transposed into K=32
        //      B-operand fragments (tokens quad*8+j contiguous per lane) ----
        bf16x8 pf[2][2];
#pragma unroll
        for (int bnd = 0; bnd < 2; bnd++)
#pragma unroll
            for (int ttp = 0; ttp < 2; ttp++) {
                unsigned A0, A1, B0, B1;
                exppack(s[bnd][2 * ttp], A0, A1);       // tokens ttp*32 + quad*4 + {0..3}
                exppack(s[bnd][2 * ttp + 1], B0, B1);   // tokens ttp*32 + 16 + quad*4 + {0..3}
                plswap32(A0, B0);
                plswap16(A0, B0);   // A0 -> frag word0, B0 -> frag word2
                plswap32(A1, B1);
                plswap16(A1, B1);   // A1 -> frag word1, B1 -> frag word3
                u32x4 fw = {A0, A1, B0, B1};
                bf16x8 p8 = __builtin_bit_cast(bf16x8, fw);
                pf[bnd][ttp] = p8;
                lac[bnd] = __builtin_amdgcn_mfma_f32_16x16x32_bf16(ONES8, p8, lac[bnd], 0, 0, 0);
            }

        // ---- O^T += V^T @ P^T (K=32; V frags shared across bands) ----
        __builtin_amdgcn_s_setprio(1);
#pragma unroll
        for (int kk = 0; kk < 2; kk++)
#pragma unroll
            for (int dd = 0; dd < 4; dd++) {
                bf16x8 vf = *(const bf16x8*)
                    &Vbuf[(size_t)((kk * 4 + quad) * 64 + dd * 16 + l) * 8];
                o[0][dd] = __builtin_amdgcn_mfma_f32_16x16x32_bf16(vf, pf[0][kk], o[0][dd], 0, 0, 0);
                o[1][dd] = __builtin_amdgcn_mfma_f32_16x16x32_bf16(vf, pf[1][kk], o[1][dd], 0, 0, 0);
            }
        __builtin_amdgcn_s_setprio(0);
        if (++bc == 3) bc = 0;
    }

    // ---- epilogue: O^T frag: col q = lane&15, row d = dd*16 + quad*4 + r ----
#pragma unroll
    for (int bnd = 0; bnd < 2; bnd++) {
        float inv = 1.f / lac[bnd][0];   // all 4 regs equal (ONES-A rows identical)
        int q = q0 + wave * 32 + bnd * 16 + l;
        size_t rowb = ((size_t)b * Sc + q) * Dc + hh * HDc + quad * 4;
#pragma unroll
        for (int dd = 0; dd < 4; dd++) {
            us4 h4, l4;
#pragma unroll
            for (int r = 0; r < 4; r++)
                split2(o[bnd][dd][r] * inv,
                       ((unsigned short*)&h4)[r], ((unsigned short*)&l4)[r]);
            *(us4*)(AOh + rowb + dd * 16) = h4;
            *(us4*)(AOl + rowb + dd * 16) = l4;
        }
    }
}

// ---------------------------------------------------------------------------
// Output projection GEMM (MFMA split-bf16 3-product, dbuf, round-8 form),
// 128x128 tile, 8 waves, SPLIT-K=2 via separate partials. UNTOUCHED.
// ---------------------------------------------------------------------------
__global__ __launch_bounds__(512, 4) void gemm_out(
    const unsigned short* __restrict__ Ah, const unsigned short* __restrict__ Al,
    const unsigned short* __restrict__ Wh, const unsigned short* __restrict__ Wl,
    float* __restrict__ C0, float* __restrict__ C1) {
    constexpr int K = 1024;
    __shared__ __align__(16) unsigned short AsH[2 * 4096], AsL[2 * 4096],
                                            BsH[2 * 4096], BsL[2 * 4096];

    const int t = threadIdx.x;
    const int lane = t & 63;
    const int wave = t >> 6;               // 0..7
    const int l = lane & 15;
    const int quad = lane >> 4;
    const int wr = wave >> 1;              // 0..3
    const int wc = wave & 1;               // 0..1
    const int m0 = blockIdx.x * 128;   // m fastest -> XCD A-locality
    const int n0 = blockIdx.y * 128;
    const int k0 = blockIdx.z * 512;   // split-K half
    float* __restrict__ C = blockIdx.z ? C1 : C0;

    // staging: thread t owns row (t&127), kcell (t>>7) of all 4 tensors.
    const int arow = t & 127, akc = t >> 7;
    const unsigned short* gah = Ah + (size_t)(m0 + arow) * K + k0 + akc * 8;
    const unsigned short* gal = Al + (size_t)(m0 + arow) * K + k0 + akc * 8;
    const unsigned short* gbh = Wh + (size_t)(n0 + arow) * K + k0 + akc * 8;
    const unsigned short* gbl = Wl + (size_t)(n0 + arow) * K + k0 + akc * 8;

    f32x4 acc[2][4];
#pragma unroll
    for (int i = 0; i < 2; i++)
#pragma unroll
        for (int j = 0; j < 4; j++) acc[i][j] = (f32x4){0.f, 0.f, 0.f, 0.f};

#define STAGE_OUT(koff, bo)                                                                \
    do {                                                                                   \
        __builtin_amdgcn_global_load_lds((gp_t)(gah + (koff)),                             \
            (lp_t)(AsH + (bo) + t * 8), 16, 0, 0);                                         \
        __builtin_amdgcn_global_load_lds((gp_t)(gal + (koff)),                             \
            (lp_t)(AsL + (bo) + t * 8), 16, 0, 0);                                         \
        __builtin_amdgcn_global_load_lds((gp_t)(gbh + (koff)),                             \
            (lp_t)(BsH + (bo) + t * 8), 16, 0, 0);                                         \
        __builtin_amdgcn_global_load_lds((gp_t)(gbl + (koff)),                             \
            (lp_t)(BsL + (bo) + t * 8), 16, 0, 0);                                         \
    } while (0)

    STAGE_OUT(0, 0);

    for (int it = 0; it < 16; ++it) {
        __syncthreads();
        if (it + 1 < 16) STAGE_OUT((it + 1) * 32, ((it + 1) & 1) * 4096);
        const int bo = (it & 1) * 4096;
        bf16x8 ah[2], al[2], bh[4], bl[4];
#pragma unroll
        for (int i = 0; i < 2; i++) {
            int ra = bo + (quad * 128 + wr * 32 + i * 16 + l) * 8;
            ah[i] = *(const bf16x8*)&AsH[ra];
            al[i] = *(const bf16x8*)&AsL[ra];
        }
#pragma unroll
        for (int j = 0; j < 4; j++) {
            int rb = bo + (quad * 128 + wc * 64 + j * 16 + l) * 8;
            bh[j] = *(const bf16x8*)&BsH[rb];
            bl[j] = *(const bf16x8*)&BsL[rb];
        }
#pragma unroll
        for (int i = 0; i < 2; i++)
#pragma unroll
            for (int j = 0; j < 4; j++) {
                acc[i][j] = __builtin_amdgcn_mfma_f32_16x16x32_bf16(ah[i], bh[j], acc[i][j], 0, 0, 0);
                acc[i][j] = __builtin_amdgcn_mfma_f32_16x16x32_bf16(al[i], bh[j], acc[i][j], 0, 0, 0);
                acc[i][j] = __builtin_amdgcn_mfma_f32_16x16x32_bf16(ah[i], bl[j], acc[i][j], 0, 0, 0);
            }
    }
#undef STAGE_OUT

#pragma unroll
    for (int i = 0; i < 2; i++)
#pragma unroll
        for (int j = 0; j < 4; j++)
#pragma unroll
            for (int r = 0; r < 4; r++) {
                int m = m0 + wr * 32 + i * 16 + quad * 4 + r;
                int n = n0 + wc * 64 + j * 16 + l;
                C[(size_t)m * Dc + n] = acc[i][j][r];
            }
}

// ---------------------------------------------------------------------------
// Split-K combine: out += P1 (float4 vectorized).
// ---------------------------------------------------------------------------
__global__ void add_partial(float* __restrict__ out, const float* __restrict__ p1) {
    int i = (blockIdx.x * 256 + threadIdx.x) * 4;
    float4 a = *(const float4*)(out + i);
    float4 b = *(const float4*)(p1 + i);
    a.x += b.x; a.y += b.y; a.z += b.z; a.w += b.w;
    *(float4*)(out + i) = a;
}

// ---------------------------------------------------------------------------
extern "C" void kernel_launch(void* const* d_in, const int* in_sizes, int n_in,
                              void* d_out, int out_size, void* d_ws, size_t ws_size,
                              hipStream_t stream) {
    const float* x  = (const float*)d_in[0];
    const float* Wq = (const float*)d_in[1];
    const float* Wk = (const float*)d_in[2];
    const float* Wv = (const float*)d_in[3];
    const float* Wo = (const float*)d_in[4];
    float* out = (float*)d_out;

    unsigned short* usw = (unsigned short*)d_ws;
    const size_t M4 = (size_t)1 << 22;   // 4M elements
    unsigned short* whAll = usw;                 // 4 x 1M weights hi
    unsigned short* wlAll = usw + M4;            // lo (only Wo slot used)
    unsigned short* xh = usw + 2 * M4;           // x hi (later AOh)
    unsigned short* xl = usw + 3 * M4;           // later AOl
    unsigned short* Qh = usw + 4 * M4;
    unsigned short* Kh = usw + 5 * M4;
    unsigned short* Vh = usw + 6 * M4;
    float* ct = (float*)(usw + 7 * M4);
    float* st_ = ct + (size_t)Sc * 32;
    unsigned short* AOh = xh;   // x dead after QKV GEMM
    unsigned short* AOl = xl;
    // split-K partial: 16 MB fp32 reusing Qh+Kh slots (dead after attn)
    float* P1 = (float*)Qh;

    // 1. RoPE table
    rope_table<<<dim3((Sc * 32) / 256), dim3(256), 0, stream>>>(ct, st_);
    // 2. convert x + weights to bf16 (Wo keeps hi/lo)
    split_xw<<<dim3(4096, 5), dim3(256), 0, stream>>>(x, Wq, Wk, Wv, Wo, xh, whAll, wlAll);
    // 3. QKV projections: 256x256 8-phase schedule (T3+T4+T5), fused epilogues
    gemm_qkv8<<<dim3(16, 4, 3), dim3(512), 0, stream>>>(
        xh, whAll, Qh, Kh, Vh, ct, st_);
    // 4. attention: 256q/block, 8 waves, 1 block/CU, counted-vmcnt triple-buffer
    attn10<<<dim3(256), dim3(512), 0, stream>>>(Qh, Kh, Vh, AOh, AOl);
    // 5. output projection: split-K=2 partials (z=0 -> out, z=1 -> P1)
    gemm_out<<<dim3(32, 8, 2), dim3(512), 0, stream>>>(
        AOh, AOl, whAll + 3 * (1 << 20), wlAll + 3 * (1 << 20), out, P1);
    // 6. combine partials
    add_partial<<<dim3(4096), dim3(256), 0, stream>>>(out, P1);
}

// Round 10
// 203.353 us; speedup vs baseline: 1.1888x; 1.1888x over previous
//
#include <hip/hip_runtime.h>
#include <math.h>

// Problem constants
constexpr int Bc = 2;
constexpr int Sc = 2048;
constexpr int Dc = 1024;
constexpr int Hc = 16;
constexpr int HDc = 64;

// Q pre-scale: attention 1/sqrt(64) folded with log2(e) for exp2-domain softmax
constexpr float QSC = 0.125f * 1.4426950408889634f;

typedef __attribute__((ext_vector_type(8))) short bf16x8;
typedef __attribute__((ext_vector_type(4))) float f32x4;
typedef __attribute__((ext_vector_type(4))) unsigned short us4;
typedef __attribute__((ext_vector_type(2))) unsigned int u32x2;
typedef __attribute__((ext_vector_type(4))) unsigned int u32x4;

typedef const __attribute__((address_space(1))) unsigned int* gp_t;
typedef __attribute__((address_space(3))) unsigned int* lp_t;

// fp32 -> bf16 round-to-nearest-even (returns low 16 bits)
__device__ __forceinline__ unsigned f2bf(float x) {
    unsigned u = __float_as_uint(x);
    return (u + 0x7FFFu + ((u >> 16) & 1u)) >> 16;
}

__device__ __forceinline__ void split2(float x, unsigned short& h, unsigned short& l) {
    unsigned hh = f2bf(x);
    h = (unsigned short)hh;
    l = (unsigned short)f2bf(x - __uint_as_float(hh << 16));
}

// gfx950 cross-lane half-swaps: a=vdst, b=src; both updated.
#if __has_builtin(__builtin_amdgcn_permlane32_swap)
__device__ __forceinline__ void plswap32(unsigned& a, unsigned& b) {
    u32x2 r = __builtin_amdgcn_permlane32_swap(a, b, false, false);
    a = r.x; b = r.y;
}
#else
__device__ __forceinline__ void plswap32(unsigned& a, unsigned& b) {
    asm volatile("v_permlane32_swap_b32 %0, %1" : "+v"(a), "+v"(b));
}
#endif
#if __has_builtin(__builtin_amdgcn_permlane16_swap)
__device__ __forceinline__ void plswap16(unsigned& a, unsigned& b) {
    u32x2 r = __builtin_amdgcn_permlane16_swap(a, b, false, false);
    a = r.x; b = r.y;
}
#else
__device__ __forceinline__ void plswap16(unsigned& a, unsigned& b) {
    asm volatile("v_permlane16_swap_b32 %0, %1" : "+v"(a), "+v"(b));
}
#endif

// exp2 of 4 S-values, packed (truncating) into two bf16-pair words:
// w0 = {bf16(s0) lo, bf16(s1) hi}, w1 = {bf16(s2) lo, bf16(s3) hi}
__device__ __forceinline__ void exppack(const f32x4& sv, unsigned& w0, unsigned& w1) {
    unsigned u0 = __float_as_uint(__builtin_amdgcn_exp2f(sv[0]));
    unsigned u1 = __float_as_uint(__builtin_amdgcn_exp2f(sv[1]));
    unsigned u2 = __float_as_uint(__builtin_amdgcn_exp2f(sv[2]));
    unsigned u3 = __float_as_uint(__builtin_amdgcn_exp2f(sv[3]));
    w0 = __builtin_amdgcn_perm(u1, u0, 0x07060302u);
    w1 = __builtin_amdgcn_perm(u3, u2, 0x07060302u);
}

// ---------------------------------------------------------------------------
// RoPE cos/sin table: [S][32] each, double precision angles.
// ---------------------------------------------------------------------------
__global__ void rope_table(float* __restrict__ ct, float* __restrict__ st_) {
    int id = blockIdx.x * 256 + threadIdx.x;
    int s = id >> 5;
    int i = id & 31;
    double invf = pow(10000.0, -(double)i / 32.0);
    double ang = (double)s * invf;
    ct[id] = (float)cos(ang);
    st_[id] = (float)sin(ang);
}

// ---------------------------------------------------------------------------
// Convert: x -> bf16 hi; Wq/Wk/Wv -> hi; Wo -> hi + lo.
// ---------------------------------------------------------------------------
__global__ void split_xw(const float* __restrict__ x,
                         const float* __restrict__ Wq, const float* __restrict__ Wk,
                         const float* __restrict__ Wv, const float* __restrict__ Wo,
                         unsigned short* __restrict__ xh,
                         unsigned short* __restrict__ whAll, unsigned short* __restrict__ wlAll) {
    int y = blockIdx.y;
    const float* src;
    unsigned short* h;
    unsigned short* l = nullptr;
    int n;
    if (y == 0) { src = x; h = xh; n = 1 << 22; }
    else {
        src = (y == 1) ? Wq : (y == 2) ? Wk : (y == 3) ? Wv : Wo;
        h = whAll + (size_t)(y - 1) * (1 << 20);
        if (y == 4) l = wlAll + (size_t)3 * (1 << 20);
        n = 1 << 20;
    }
    int i = (blockIdx.x * 256 + threadIdx.x) * 4;
    if (i >= n) return;
    float4 v = *(const float4*)(src + i);
    us4 hh;
    ((unsigned short*)&hh)[0] = (unsigned short)f2bf(v.x);
    ((unsigned short*)&hh)[1] = (unsigned short)f2bf(v.y);
    ((unsigned short*)&hh)[2] = (unsigned short)f2bf(v.z);
    ((unsigned short*)&hh)[3] = (unsigned short)f2bf(v.w);
    *(us4*)(h + i) = hh;
    if (l) {
        us4 ll;
        const float* vp = (const float*)&v;
#pragma unroll
        for (int e = 0; e < 4; e++) {
            unsigned short hi = ((unsigned short*)&hh)[e];
            ((unsigned short*)&ll)[e] =
                (unsigned short)f2bf(vp[e] - __uint_as_float((unsigned)hi << 16));
        }
        *(us4*)(l + i) = ll;
    }
}

// ---------------------------------------------------------------------------
// QKV GEMM v9: 128x128 tile, BK=64, dbuf, 8 waves — COALESCED staging.
// Each gload_lds instruction covers 8 rows x 128B CONTIGUOUS (8 line-requests
// vs 64 in the old row-per-lane layout). LDS [row128][chunk8][8sh] with XOR
// swizzle chunk^=(row&7) applied on BOTH the pre-swizzled global source and
// the ds_read side (LDS dst stays linear — gload_lds requirement). Read-side
// bank pattern: 2-way (free). Epilogues identical to the proven r8 kernel.
// ---------------------------------------------------------------------------
__global__ __launch_bounds__(512, 4) void gemm_qkv9(
    const unsigned short* __restrict__ Ah,
    const unsigned short* __restrict__ whAll,
    unsigned short* __restrict__ Qh,
    unsigned short* __restrict__ Kh,
    unsigned short* __restrict__ Vh,
    const float* __restrict__ ct, const float* __restrict__ st_) {
    constexpr int K = 1024;
    // [buf][row 128][chunk 8][8 shorts] = 16 KB per tensor per buf
    __shared__ __align__(16) unsigned short As[2][8192], Bs[2][8192];

    const int t = threadIdx.x;
    const int lane = t & 63;
    const int wave = t >> 6;               // 0..7
    const int l15 = lane & 15;
    const int quad = lane >> 4;
    const int wr = wave >> 1;              // 0..3: 32-row strip
    const int wc = wave & 1;               // 0..1: 64-col strip (= head)
    const int m0 = blockIdx.x * 128;
    const int n0 = blockIdx.y * 128;
    const int z = blockIdx.z;
    const unsigned short* Wh = whAll + (size_t)z * (1 << 20);

    // staging chunks: c = t and t+512; row = c>>3, slot = c&7,
    // global chunk = slot ^ (row&7)  (pre-swizzled source)
    const int c0 = t,        r0 = c0 >> 3, s0 = c0 & 7;
    const int c1 = t + 512,  r1 = c1 >> 3, s1 = c1 & 7;
    const unsigned short* gA0 = Ah + (size_t)(m0 + r0) * K + (s0 ^ (r0 & 7)) * 8;
    const unsigned short* gA1 = Ah + (size_t)(m0 + r1) * K + (s1 ^ (r1 & 7)) * 8;
    const unsigned short* gB0 = Wh + (size_t)(n0 + r0) * K + (s0 ^ (r0 & 7)) * 8;
    const unsigned short* gB1 = Wh + (size_t)(n0 + r1) * K + (s1 ^ (r1 & 7)) * 8;
    const int d0 = c0 * 8, d1 = c1 * 8;    // linear LDS dst (shorts)

    f32x4 acc[2][4];
#pragma unroll
    for (int i = 0; i < 2; i++)
#pragma unroll
        for (int j = 0; j < 4; j++) acc[i][j] = (f32x4){0.f, 0.f, 0.f, 0.f};

#define STGQ(X) do {                                                                       \
        const int _ko = (X) * 64;                                                          \
        const int _bf = (X) & 1;                                                           \
        __builtin_amdgcn_global_load_lds((gp_t)(gA0 + _ko), (lp_t)(&As[_bf][d0]), 16, 0, 0); \
        __builtin_amdgcn_global_load_lds((gp_t)(gA1 + _ko), (lp_t)(&As[_bf][d1]), 16, 0, 0); \
        __builtin_amdgcn_global_load_lds((gp_t)(gB0 + _ko), (lp_t)(&Bs[_bf][d0]), 16, 0, 0); \
        __builtin_amdgcn_global_load_lds((gp_t)(gB1 + _ko), (lp_t)(&Bs[_bf][d1]), 16, 0, 0); \
    } while (0)

    STGQ(0);

    for (int it = 0; it < 16; ++it) {
        __syncthreads();
        if (it + 1 < 16) STGQ(it + 1);
        const unsigned short* a = &As[it & 1][0];
        const unsigned short* bb = &Bs[it & 1][0];
#pragma unroll
        for (int ks = 0; ks < 2; ks++) {
            bf16x8 ah[2], bh[4];
#pragma unroll
            for (int i = 0; i < 2; i++) {
                int row = wr * 32 + i * 16 + l15;
                ah[i] = *(const bf16x8*)&a[row * 64 + ((ks * 4 + quad) ^ (row & 7)) * 8];
            }
#pragma unroll
            for (int j = 0; j < 4; j++) {
                int row = wc * 64 + j * 16 + l15;
                bh[j] = *(const bf16x8*)&bb[row * 64 + ((ks * 4 + quad) ^ (row & 7)) * 8];
            }
#pragma unroll
            for (int i = 0; i < 2; i++)
#pragma unroll
                for (int j = 0; j < 4; j++)
                    acc[i][j] = __builtin_amdgcn_mfma_f32_16x16x32_bf16(ah[i], bh[j], acc[i][j], 0, 0, 0);
        }
    }
#undef STGQ

    // ---- fused epilogue (identical to proven r8 kernel) ----
    const int hcol = blockIdx.y * 2 + wc;   // head index 0..15
    if (z == 2) {
        // V^T cells, K=32 A-operand layout:
        //   off = ((kk*4 + qd)*64 + d)*8 + tj, tok64 = kk*32 + qd*8 + tj
        // acc[i][jj][r]: tok64 = ii*16 + quad*4 + r with ii = (2*wr+i)&3
#pragma unroll
        for (int i = 0; i < 2; i++) {
            int m_base = m0 + wr * 32 + i * 16 + quad * 4;
            int bbk = m_base >> 11;
            int T = (m_base & (Sc - 1)) >> 6;
            int ii = (2 * wr + i) & 3;
            int kk = ii >> 1;
            int qd = ((ii & 1) << 1) | (quad >> 1);
            int tj = (quad & 1) * 4;
            size_t tilebase = (((size_t)(bbk * Hc + hcol)) * 32 + T) * 4096;
#pragma unroll
            for (int jj = 0; jj < 4; jj++) {
                int d = jj * 16 + l15;
                size_t off = tilebase + (size_t)(((kk * 4 + qd) * 64 + d) * 8 + tj);
                us4 v4;
#pragma unroll
                for (int r = 0; r < 4; r++)
                    ((unsigned short*)&v4)[r] = (unsigned short)f2bf(acc[i][jj][r]);
                *(us4*)(Vh + off) = v4;
            }
        }
    } else {
#pragma unroll
        for (int i = 0; i < 2; i++)
#pragma unroll
            for (int r = 0; r < 4; r++) {
                int m = m0 + wr * 32 + i * 16 + quad * 4 + r;
                int bbk = m >> 11, s = m & (Sc - 1);
#pragma unroll
                for (int jp = 0; jp < 2; jp++) {
                    int d = jp * 16 + l15;                     // 0..31
                    float cs = ct[s * 32 + d];
                    float sn = st_[s * 32 + d];
                    float x0 = acc[i][jp][r];
                    float x1 = acc[i][jp + 2][r];
                    float y0 = x0 * cs - x1 * sn;
                    float y1 = x1 * cs + x0 * sn;
                    if (z == 0) {
                        size_t rowb = (((size_t)(bbk * Hc + hcol)) * Sc + s) * HDc;
                        Qh[rowb + d]      = (unsigned short)f2bf(y0 * QSC);
                        Qh[rowb + d + 32] = (unsigned short)f2bf(y1 * QSC);
                    } else {
                        int T = s >> 6, tok = s & 63;
                        size_t tb = (((size_t)(bbk * Hc + hcol)) * 32 + T) * 8;
                        size_t off0 = ((tb + (d >> 3)) * 64 + tok) * 8 + (d & 7);
                        size_t off1 = ((tb + (d >> 3) + 4) * 64 + tok) * 8 + (d & 7);
                        Kh[off0] = (unsigned short)f2bf(y0);
                        Kh[off1] = (unsigned short)f2bf(y1);
                    }
                }
            }
    }
}

// ---------------------------------------------------------------------------
// MFMA flash attention v10: all-K=32 MFMA, 256 q/block (8 waves x 2 bands),
// grid 256 = 1 block/CU. Triple-buffered K/V + per-wave counted vmcnt(2)
// before raw s_barrier. Staging already fully coalesced. UNTOUCHED.
// ---------------------------------------------------------------------------
__global__ __launch_bounds__(512) void attn10(
    const unsigned short* __restrict__ Qh,
    const unsigned short* __restrict__ Kh,
    const unsigned short* __restrict__ Vh,
    unsigned short* __restrict__ AOh, unsigned short* __restrict__ AOl) {
    __shared__ __align__(16) unsigned short KsH[3 * 4096], VtH[3 * 4096];

    const int t = threadIdx.x;
    const int lane = t & 63;
    const int wave = t >> 6;               // 0..7
    const int l = lane & 15;
    const int quad = lane >> 4;
    const int id = blockIdx.x;             // 0..255
    const int bh = (id & 7) * 4 + (id >> 6);   // XCD-clustered (4 bh / XCD slot)
    const int qt = (id >> 3) & 7;
    const int q0 = qt * 256;
    const int b = bh >> 4;
    const int hh = bh & 15;

    const bf16x8 ONES8 = {(short)0x3F80, (short)0x3F80, (short)0x3F80, (short)0x3F80,
                          (short)0x3F80, (short)0x3F80, (short)0x3F80, (short)0x3F80};

    // Q fragments (B operand: n=q=lane&15, k=d=quad*8+j); band bnd -> rows
    // q0 + wave*32 + bnd*16 + l
    bf16x8 qf[2][2];
#pragma unroll
    for (int bnd = 0; bnd < 2; bnd++) {
        size_t rowb = ((size_t)bh * Sc + q0 + wave * 32 + bnd * 16 + l) * HDc;
#pragma unroll
        for (int ks = 0; ks < 2; ks++)
            qf[bnd][ks] = *(const bf16x8*)(Qh + rowb + ks * 32 + quad * 8);
    }

    f32x4 o[2][4], lac[2];
#pragma unroll
    for (int bnd = 0; bnd < 2; bnd++) {
        lac[bnd] = (f32x4){0.f, 0.f, 0.f, 0.f};
#pragma unroll
        for (int i = 0; i < 4; i++) o[bnd][i] = (f32x4){0.f, 0.f, 0.f, 0.f};
    }

    // staging: 16 chunks of 512 elems per kt (K: 0-7, V: 8-15); wave w owns
    // chunks w*2, w*2+1 (waves 0-3 -> K, waves 4-7 -> V). LDS dst uniform.
    const int tensor = wave >> 2;          // 0 = K, 1 = V
    const int coff0 = (wave * 2) & 7;      // 0,2,4,6
    unsigned short* larr = tensor ? VtH : KsH;
    const unsigned short* gT =
        (tensor ? Vh : Kh) + (size_t)bh * Sc * HDc + coff0 * 512 + lane * 8;

    // prologue: kt=0 into buffer 0
#pragma unroll
    for (int q = 0; q < 2; q++)
        __builtin_amdgcn_global_load_lds(
            (gp_t)(gT + q * 512),
            (lp_t)(larr + coff0 * 512 + q * 512),
            16, 0, 0);

    int bc = 0;   // kt % 3
    for (int kt = 0; kt < 32; kt++) {
        if (kt + 1 < 32) {
            int nb = bc + 1; if (nb == 3) nb = 0;     // (kt+1) % 3
            const unsigned short* g = gT + (size_t)(kt + 1) * 4096;
            unsigned short* dst = larr + nb * 4096 + coff0 * 512;
#pragma unroll
            for (int q = 0; q < 2; q++)
                __builtin_amdgcn_global_load_lds(
                    (gp_t)(g + q * 512),
                    (lp_t)(dst + q * 512),
                    16, 0, 0);
            asm volatile("s_waitcnt vmcnt(2)" ::: "memory");   // own kt-loads landed
        } else {
            asm volatile("s_waitcnt vmcnt(0)" ::: "memory");
        }
        __builtin_amdgcn_s_barrier();                          // all waves' kt-loads landed
        const unsigned short* Kbuf = KsH + bc * 4096;
        const unsigned short* Vbuf = VtH + bc * 4096;

        // ---- S^T = K @ Q^T: A=K frag (m=tok), B=Q frag (n=q) ----
        f32x4 s[2][4];
#pragma unroll
        for (int bnd = 0; bnd < 2; bnd++)
#pragma unroll
            for (int tt = 0; tt < 4; tt++) s[bnd][tt] = (f32x4){0.f, 0.f, 0.f, 0.f};
        __builtin_amdgcn_s_setprio(1);
#pragma unroll
        for (int ks = 0; ks < 2; ks++)
#pragma unroll
            for (int tt = 0; tt < 4; tt++) {
                bf16x8 kf = *(const bf16x8*)&Kbuf[((ks * 4 + quad) * 64 + tt * 16 + l) * 8];
                s[0][tt] = __builtin_amdgcn_mfma_f32_16x16x32_bf16(kf, qf[0][ks], s[0][tt], 0, 0, 0);
                s[1][tt] = __builtin_amdgcn_mfma_f32_16x16x32_bf16(kf, qf[1][ks], s[1][tt], 0, 0, 0);
            }
        __builtin_amdgcn_s_setprio(0);

        // ---- P^T = exp2(S^T), packed + permlane-transposed into K=32
        //      B-operand fragments (tokens quad*8+j contiguous per lane) ----
        bf16x8 pf[2][2];
#pragma unroll
        for (int bnd = 0; bnd < 2; bnd++)
#pragma unroll
            for (int ttp = 0; ttp < 2; ttp++) {
                unsigned A0, A1, B0, B1;
                exppack(s[bnd][2 * ttp], A0, A1);       // tokens ttp*32 + quad*4 + {0..3}
                exppack(s[bnd][2 * ttp + 1], B0, B1);   // tokens ttp*32 + 16 + quad*4 + {0..3}
                plswap32(A0, B0);
                plswap16(A0, B0);   // A0 -> frag word0, B0 -> frag word2
                plswap32(A1, B1);
                plswap16(A1, B1);   // A1 -> frag word1, B1 -> frag word3
                u32x4 fw = {A0, A1, B0, B1};
                bf16x8 p8 = __builtin_bit_cast(bf16x8, fw);
                pf[bnd][ttp] = p8;
                lac[bnd] = __builtin_amdgcn_mfma_f32_16x16x32_bf16(ONES8, p8, lac[bnd], 0, 0, 0);
            }

        // ---- O^T += V^T @ P^T (K=32; V frags shared across bands) ----
        __builtin_amdgcn_s_setprio(1);
#pragma unroll
        for (int kk = 0; kk < 2; kk++)
#pragma unroll
            for (int dd = 0; dd < 4; dd++) {
                bf16x8 vf = *(const bf16x8*)
                    &Vbuf[(size_t)((kk * 4 + quad) * 64 + dd * 16 + l) * 8];
                o[0][dd] = __builtin_amdgcn_mfma_f32_16x16x32_bf16(vf, pf[0][kk], o[0][dd], 0, 0, 0);
                o[1][dd] = __builtin_amdgcn_mfma_f32_16x16x32_bf16(vf, pf[1][kk], o[1][dd], 0, 0, 0);
            }
        __builtin_amdgcn_s_setprio(0);
        if (++bc == 3) bc = 0;
    }

    // ---- epilogue: O^T frag: col q = lane&15, row d = dd*16 + quad*4 + r ----
#pragma unroll
    for (int bnd = 0; bnd < 2; bnd++) {
        float inv = 1.f / lac[bnd][0];   // all 4 regs equal (ONES-A rows identical)
        int q = q0 + wave * 32 + bnd * 16 + l;
        size_t rowb = ((size_t)b * Sc + q) * Dc + hh * HDc + quad * 4;
#pragma unroll
        for (int dd = 0; dd < 4; dd++) {
            us4 h4, l4;
#pragma unroll
            for (int r = 0; r < 4; r++)
                split2(o[bnd][dd][r] * inv,
                       ((unsigned short*)&h4)[r], ((unsigned short*)&l4)[r]);
            *(us4*)(AOh + rowb + dd * 16) = h4;
            *(us4*)(AOl + rowb + dd * 16) = l4;
        }
    }
}

// ---------------------------------------------------------------------------
// Output projection GEMM v9 (split-bf16 3-product, dbuf, split-K=2 partials):
// COALESCED staging — [row128][chunk4][8sh] cells, each gload_lds covers 16
// rows x 64B (16 line-requests vs 64). XOR swizzle chunk^=(row&3) on source
// and read side (worst 4-way read conflict, ~1.58x on reads only).
// ---------------------------------------------------------------------------
__global__ __launch_bounds__(512, 4) void gemm_out9(
    const unsigned short* __restrict__ Ah, const unsigned short* __restrict__ Al,
    const unsigned short* __restrict__ Wh, const unsigned short* __restrict__ Wl,
    float* __restrict__ C0, float* __restrict__ C1) {
    constexpr int K = 1024;
    // [buf][row 128][chunk 4][8 shorts] = 8 KB per tensor per buf
    __shared__ __align__(16) unsigned short AsH[2][4096], AsL[2][4096],
                                            BsH[2][4096], BsL[2][4096];

    const int t = threadIdx.x;
    const int lane = t & 63;
    const int wave = t >> 6;               // 0..7
    const int l15 = lane & 15;
    const int quad = lane >> 4;
    const int wr = wave >> 1;              // 0..3
    const int wc = wave & 1;               // 0..1
    const int m0 = blockIdx.x * 128;   // m fastest -> XCD A-locality
    const int n0 = blockIdx.y * 128;
    const int k0 = blockIdx.z * 512;   // split-K half
    float* __restrict__ C = blockIdx.z ? C1 : C0;

    // staging: chunk c = t; row = c>>2, slot = c&3, global chunk = slot^(row&3)
    const int rr = t >> 2, ss = t & 3;
    const int gc = (ss ^ (rr & 3)) * 8;
    const unsigned short* gah = Ah + (size_t)(m0 + rr) * K + k0 + gc;
    const unsigned short* gal = Al + (size_t)(m0 + rr) * K + k0 + gc;
    const unsigned short* gbh = Wh + (size_t)(n0 + rr) * K + k0 + gc;
    const unsigned short* gbl = Wl + (size_t)(n0 + rr) * K + k0 + gc;
    const int dd_ = t * 8;                 // linear LDS dst (shorts)

    f32x4 acc[2][4];
#pragma unroll
    for (int i = 0; i < 2; i++)
#pragma unroll
        for (int j = 0; j < 4; j++) acc[i][j] = (f32x4){0.f, 0.f, 0.f, 0.f};

#define STGO(X) do {                                                                       \
        const int _ko = (X) * 32;                                                          \
        const int _bf = (X) & 1;                                                           \
        __builtin_amdgcn_global_load_lds((gp_t)(gah + _ko), (lp_t)(&AsH[_bf][dd_]), 16, 0, 0); \
        __builtin_amdgcn_global_load_lds((gp_t)(gal + _ko), (lp_t)(&AsL[_bf][dd_]), 16, 0, 0); \
        __builtin_amdgcn_global_load_lds((gp_t)(gbh + _ko), (lp_t)(&BsH[_bf][dd_]), 16, 0, 0); \
        __builtin_amdgcn_global_load_lds((gp_t)(gbl + _ko), (lp_t)(&BsL[_bf][dd_]), 16, 0, 0); \
    } while (0)

    STGO(0);

    for (int it = 0; it < 16; ++it) {
        __syncthreads();
        if (it + 1 < 16) STGO(it + 1);
        const int bf = it & 1;
        bf16x8 ah[2], al[2], bh[4], bl[4];
#pragma unroll
        for (int i = 0; i < 2; i++) {
            int row = wr * 32 + i * 16 + l15;
            int ra = row * 32 + (quad ^ (row & 3)) * 8;
            ah[i] = *(const bf16x8*)&AsH[bf][ra];
            al[i] = *(const bf16x8*)&AsL[bf][ra];
        }
#pragma unroll
        for (int j = 0; j < 4; j++) {
            int row = wc * 64 + j * 16 + l15;
            int rb = row * 32 + (quad ^ (row & 3)) * 8;
            bh[j] = *(const bf16x8*)&BsH[bf][rb];
            bl[j] = *(const bf16x8*)&BsL[bf][rb];
        }
#pragma unroll
        for (int i = 0; i < 2; i++)
#pragma unroll
            for (int j = 0; j < 4; j++) {
                acc[i][j] = __builtin_amdgcn_mfma_f32_16x16x32_bf16(ah[i], bh[j], acc[i][j], 0, 0, 0);
                acc[i][j] = __builtin_amdgcn_mfma_f32_16x16x32_bf16(al[i], bh[j], acc[i][j], 0, 0, 0);
                acc[i][j] = __builtin_amdgcn_mfma_f32_16x16x32_bf16(ah[i], bl[j], acc[i][j], 0, 0, 0);
            }
    }
#undef STGO

#pragma unroll
    for (int i = 0; i < 2; i++)
#pragma unroll
        for (int j = 0; j < 4; j++)
#pragma unroll
            for (int r = 0; r < 4; r++) {
                int m = m0 + wr * 32 + i * 16 + quad * 4 + r;
                int n = n0 + wc * 64 + j * 16 + l15;
                C[(size_t)m * Dc + n] = acc[i][j][r];
            }
}

// ---------------------------------------------------------------------------
// Split-K combine: out += P1 (float4 vectorized).
// ---------------------------------------------------------------------------
__global__ void add_partial(float* __restrict__ out, const float* __restrict__ p1) {
    int i = (blockIdx.x * 256 + threadIdx.x) * 4;
    float4 a = *(const float4*)(out + i);
    float4 b = *(const float4*)(p1 + i);
    a.x += b.x; a.y += b.y; a.z += b.z; a.w += b.w;
    *(float4*)(out + i) = a;
}

// ---------------------------------------------------------------------------
extern "C" void kernel_launch(void* const* d_in, const int* in_sizes, int n_in,
                              void* d_out, int out_size, void* d_ws, size_t ws_size,
                              hipStream_t stream) {
    const float* x  = (const float*)d_in[0];
    const float* Wq = (const float*)d_in[1];
    const float* Wk = (const float*)d_in[2];
    const float* Wv = (const float*)d_in[3];
    const float* Wo = (const float*)d_in[4];
    float* out = (float*)d_out;

    unsigned short* usw = (unsigned short*)d_ws;
    const size_t M4 = (size_t)1 << 22;   // 4M elements
    unsigned short* whAll = usw;                 // 4 x 1M weights hi
    unsigned short* wlAll = usw + M4;            // lo (only Wo slot used)
    unsigned short* xh = usw + 2 * M4;           // x hi (later AOh)
    unsigned short* xl = usw + 3 * M4;           // later AOl
    unsigned short* Qh = usw + 4 * M4;
    unsigned short* Kh = usw + 5 * M4;
    unsigned short* Vh = usw + 6 * M4;
    float* ct = (float*)(usw + 7 * M4);
    float* st_ = ct + (size_t)Sc * 32;
    unsigned short* AOh = xh;   // x dead after QKV GEMM
    unsigned short* AOl = xl;
    // split-K partial: 16 MB fp32 reusing Qh+Kh slots (dead after attn)
    float* P1 = (float*)Qh;

    // 1. RoPE table
    rope_table<<<dim3((Sc * 32) / 256), dim3(256), 0, stream>>>(ct, st_);
    // 2. convert x + weights to bf16 (Wo keeps hi/lo)
    split_xw<<<dim3(4096, 5), dim3(256), 0, stream>>>(x, Wq, Wk, Wv, Wo, xh, whAll, wlAll);
    // 3. QKV projections: coalesced BK=64 staging + XOR swizzle, fused epilogues
    gemm_qkv9<<<dim3(32, 8, 3), dim3(512), 0, stream>>>(
        xh, whAll, Qh, Kh, Vh, ct, st_);
    // 4. attention: 256q/block, 8 waves, 1 block/CU, counted-vmcnt triple-buffer
    attn10<<<dim3(256), dim3(512), 0, stream>>>(Qh, Kh, Vh, AOh, AOl);
    // 5. output projection: coalesced staging, split-K=2 partials
    gemm_out9<<<dim3(32, 8, 2), dim3(512), 0, stream>>>(
        AOh, AOl, whAll + 3 * (1 << 20), wlAll + 3 * (1 << 20), out, P1);
    // 6. combine partials
    add_partial<<<dim3(4096), dim3(256), 0, stream>>>(out, P1);
}

// Round 11
// 197.524 us; speedup vs baseline: 1.2238x; 1.0295x over previous
//
#include <hip/hip_runtime.h>
#include <math.h>

// Problem constants
constexpr int Bc = 2;
constexpr int Sc = 2048;
constexpr int Dc = 1024;
constexpr int Hc = 16;
constexpr int HDc = 64;

// Q pre-scale: attention 1/sqrt(64) folded with log2(e) for exp2-domain softmax
constexpr float QSC = 0.125f * 1.4426950408889634f;

typedef __attribute__((ext_vector_type(8))) short bf16x8;
typedef __attribute__((ext_vector_type(4))) float f32x4;
typedef __attribute__((ext_vector_type(4))) unsigned short us4;
typedef __attribute__((ext_vector_type(2))) unsigned int u32x2;
typedef __attribute__((ext_vector_type(4))) unsigned int u32x4;

typedef const __attribute__((address_space(1))) unsigned int* gp_t;
typedef __attribute__((address_space(3))) unsigned int* lp_t;

// fp32 -> bf16 round-to-nearest-even (returns low 16 bits)
__device__ __forceinline__ unsigned f2bf(float x) {
    unsigned u = __float_as_uint(x);
    return (u + 0x7FFFu + ((u >> 16) & 1u)) >> 16;
}

__device__ __forceinline__ void split2(float x, unsigned short& h, unsigned short& l) {
    unsigned hh = f2bf(x);
    h = (unsigned short)hh;
    l = (unsigned short)f2bf(x - __uint_as_float(hh << 16));
}

// gfx950 cross-lane half-swaps: a=vdst, b=src; both updated.
#if __has_builtin(__builtin_amdgcn_permlane32_swap)
__device__ __forceinline__ void plswap32(unsigned& a, unsigned& b) {
    u32x2 r = __builtin_amdgcn_permlane32_swap(a, b, false, false);
    a = r.x; b = r.y;
}
#else
__device__ __forceinline__ void plswap32(unsigned& a, unsigned& b) {
    asm volatile("v_permlane32_swap_b32 %0, %1" : "+v"(a), "+v"(b));
}
#endif
#if __has_builtin(__builtin_amdgcn_permlane16_swap)
__device__ __forceinline__ void plswap16(unsigned& a, unsigned& b) {
    u32x2 r = __builtin_amdgcn_permlane16_swap(a, b, false, false);
    a = r.x; b = r.y;
}
#else
__device__ __forceinline__ void plswap16(unsigned& a, unsigned& b) {
    asm volatile("v_permlane16_swap_b32 %0, %1" : "+v"(a), "+v"(b));
}
#endif

// exp2 of 4 S-values, packed (truncating) into two bf16-pair words:
// w0 = {bf16(s0) lo, bf16(s1) hi}, w1 = {bf16(s2) lo, bf16(s3) hi}
__device__ __forceinline__ void exppack(const f32x4& sv, unsigned& w0, unsigned& w1) {
    unsigned u0 = __float_as_uint(__builtin_amdgcn_exp2f(sv[0]));
    unsigned u1 = __float_as_uint(__builtin_amdgcn_exp2f(sv[1]));
    unsigned u2 = __float_as_uint(__builtin_amdgcn_exp2f(sv[2]));
    unsigned u3 = __float_as_uint(__builtin_amdgcn_exp2f(sv[3]));
    w0 = __builtin_amdgcn_perm(u1, u0, 0x07060302u);
    w1 = __builtin_amdgcn_perm(u3, u2, 0x07060302u);
}

// ---------------------------------------------------------------------------
// RoPE cos/sin table: [S][32] each, double precision angles.
// ---------------------------------------------------------------------------
__global__ void rope_table(float* __restrict__ ct, float* __restrict__ st_) {
    int id = blockIdx.x * 256 + threadIdx.x;
    int s = id >> 5;
    int i = id & 31;
    double invf = pow(10000.0, -(double)i / 32.0);
    double ang = (double)s * invf;
    ct[id] = (float)cos(ang);
    st_[id] = (float)sin(ang);
}

// ---------------------------------------------------------------------------
// Convert: x -> bf16 hi; Wq/Wk/Wv -> hi; Wo -> hi + lo.
// ---------------------------------------------------------------------------
__global__ void split_xw(const float* __restrict__ x,
                         const float* __restrict__ Wq, const float* __restrict__ Wk,
                         const float* __restrict__ Wv, const float* __restrict__ Wo,
                         unsigned short* __restrict__ xh,
                         unsigned short* __restrict__ whAll, unsigned short* __restrict__ wlAll) {
    int y = blockIdx.y;
    const float* src;
    unsigned short* h;
    unsigned short* l = nullptr;
    int n;
    if (y == 0) { src = x; h = xh; n = 1 << 22; }
    else {
        src = (y == 1) ? Wq : (y == 2) ? Wk : (y == 3) ? Wv : Wo;
        h = whAll + (size_t)(y - 1) * (1 << 20);
        if (y == 4) l = wlAll + (size_t)3 * (1 << 20);
        n = 1 << 20;
    }
    int i = (blockIdx.x * 256 + threadIdx.x) * 4;
    if (i >= n) return;
    float4 v = *(const float4*)(src + i);
    us4 hh;
    ((unsigned short*)&hh)[0] = (unsigned short)f2bf(v.x);
    ((unsigned short*)&hh)[1] = (unsigned short)f2bf(v.y);
    ((unsigned short*)&hh)[2] = (unsigned short)f2bf(v.z);
    ((unsigned short*)&hh)[3] = (unsigned short)f2bf(v.w);
    *(us4*)(h + i) = hh;
    if (l) {
        us4 ll;
        const float* vp = (const float*)&v;
#pragma unroll
        for (int e = 0; e < 4; e++) {
            unsigned short hi = ((unsigned short*)&hh)[e];
            ((unsigned short*)&ll)[e] =
                (unsigned short)f2bf(vp[e] - __uint_as_float((unsigned)hi << 16));
        }
        *(us4*)(l + i) = ll;
    }
}

// ---------------------------------------------------------------------------
// QKV GEMM v9: 128x128 tile, BK=64, dbuf, 8 waves — COALESCED staging
// (round-10 proven). UNTOUCHED.
// ---------------------------------------------------------------------------
__global__ __launch_bounds__(512, 4) void gemm_qkv9(
    const unsigned short* __restrict__ Ah,
    const unsigned short* __restrict__ whAll,
    unsigned short* __restrict__ Qh,
    unsigned short* __restrict__ Kh,
    unsigned short* __restrict__ Vh,
    const float* __restrict__ ct, const float* __restrict__ st_) {
    constexpr int K = 1024;
    // [buf][row 128][chunk 8][8 shorts] = 16 KB per tensor per buf
    __shared__ __align__(16) unsigned short As[2][8192], Bs[2][8192];

    const int t = threadIdx.x;
    const int lane = t & 63;
    const int wave = t >> 6;               // 0..7
    const int l15 = lane & 15;
    const int quad = lane >> 4;
    const int wr = wave >> 1;              // 0..3: 32-row strip
    const int wc = wave & 1;               // 0..1: 64-col strip (= head)
    const int m0 = blockIdx.x * 128;
    const int n0 = blockIdx.y * 128;
    const int z = blockIdx.z;
    const unsigned short* Wh = whAll + (size_t)z * (1 << 20);

    // staging chunks: c = t and t+512; row = c>>3, slot = c&7,
    // global chunk = slot ^ (row&7)  (pre-swizzled source)
    const int c0 = t,        r0 = c0 >> 3, s0 = c0 & 7;
    const int c1 = t + 512,  r1 = c1 >> 3, s1 = c1 & 7;
    const unsigned short* gA0 = Ah + (size_t)(m0 + r0) * K + (s0 ^ (r0 & 7)) * 8;
    const unsigned short* gA1 = Ah + (size_t)(m0 + r1) * K + (s1 ^ (r1 & 7)) * 8;
    const unsigned short* gB0 = Wh + (size_t)(n0 + r0) * K + (s0 ^ (r0 & 7)) * 8;
    const unsigned short* gB1 = Wh + (size_t)(n0 + r1) * K + (s1 ^ (r1 & 7)) * 8;
    const int d0 = c0 * 8, d1 = c1 * 8;    // linear LDS dst (shorts)

    f32x4 acc[2][4];
#pragma unroll
    for (int i = 0; i < 2; i++)
#pragma unroll
        for (int j = 0; j < 4; j++) acc[i][j] = (f32x4){0.f, 0.f, 0.f, 0.f};

#define STGQ(X) do {                                                                       \
        const int _ko = (X) * 64;                                                          \
        const int _bf = (X) & 1;                                                           \
        __builtin_amdgcn_global_load_lds((gp_t)(gA0 + _ko), (lp_t)(&As[_bf][d0]), 16, 0, 0); \
        __builtin_amdgcn_global_load_lds((gp_t)(gA1 + _ko), (lp_t)(&As[_bf][d1]), 16, 0, 0); \
        __builtin_amdgcn_global_load_lds((gp_t)(gB0 + _ko), (lp_t)(&Bs[_bf][d0]), 16, 0, 0); \
        __builtin_amdgcn_global_load_lds((gp_t)(gB1 + _ko), (lp_t)(&Bs[_bf][d1]), 16, 0, 0); \
    } while (0)

    STGQ(0);

    for (int it = 0; it < 16; ++it) {
        __syncthreads();
        if (it + 1 < 16) STGQ(it + 1);
        const unsigned short* a = &As[it & 1][0];
        const unsigned short* bb = &Bs[it & 1][0];
#pragma unroll
        for (int ks = 0; ks < 2; ks++) {
            bf16x8 ah[2], bh[4];
#pragma unroll
            for (int i = 0; i < 2; i++) {
                int row = wr * 32 + i * 16 + l15;
                ah[i] = *(const bf16x8*)&a[row * 64 + ((ks * 4 + quad) ^ (row & 7)) * 8];
            }
#pragma unroll
            for (int j = 0; j < 4; j++) {
                int row = wc * 64 + j * 16 + l15;
                bh[j] = *(const bf16x8*)&bb[row * 64 + ((ks * 4 + quad) ^ (row & 7)) * 8];
            }
#pragma unroll
            for (int i = 0; i < 2; i++)
#pragma unroll
                for (int j = 0; j < 4; j++)
                    acc[i][j] = __builtin_amdgcn_mfma_f32_16x16x32_bf16(ah[i], bh[j], acc[i][j], 0, 0, 0);
        }
    }
#undef STGQ

    // ---- fused epilogue (identical to proven r8 kernel) ----
    const int hcol = blockIdx.y * 2 + wc;   // head index 0..15
    if (z == 2) {
        // V^T cells, K=32 A-operand layout:
        //   off = ((kk*4 + qd)*64 + d)*8 + tj, tok64 = kk*32 + qd*8 + tj
        // acc[i][jj][r]: tok64 = ii*16 + quad*4 + r with ii = (2*wr+i)&3
#pragma unroll
        for (int i = 0; i < 2; i++) {
            int m_base = m0 + wr * 32 + i * 16 + quad * 4;
            int bbk = m_base >> 11;
            int T = (m_base & (Sc - 1)) >> 6;
            int ii = (2 * wr + i) & 3;
            int kk = ii >> 1;
            int qd = ((ii & 1) << 1) | (quad >> 1);
            int tj = (quad & 1) * 4;
            size_t tilebase = (((size_t)(bbk * Hc + hcol)) * 32 + T) * 4096;
#pragma unroll
            for (int jj = 0; jj < 4; jj++) {
                int d = jj * 16 + l15;
                size_t off = tilebase + (size_t)(((kk * 4 + qd) * 64 + d) * 8 + tj);
                us4 v4;
#pragma unroll
                for (int r = 0; r < 4; r++)
                    ((unsigned short*)&v4)[r] = (unsigned short)f2bf(acc[i][jj][r]);
                *(us4*)(Vh + off) = v4;
            }
        }
    } else {
#pragma unroll
        for (int i = 0; i < 2; i++)
#pragma unroll
            for (int r = 0; r < 4; r++) {
                int m = m0 + wr * 32 + i * 16 + quad * 4 + r;
                int bbk = m >> 11, s = m & (Sc - 1);
#pragma unroll
                for (int jp = 0; jp < 2; jp++) {
                    int d = jp * 16 + l15;                     // 0..31
                    float cs = ct[s * 32 + d];
                    float sn = st_[s * 32 + d];
                    float x0 = acc[i][jp][r];
                    float x1 = acc[i][jp + 2][r];
                    float y0 = x0 * cs - x1 * sn;
                    float y1 = x1 * cs + x0 * sn;
                    if (z == 0) {
                        size_t rowb = (((size_t)(bbk * Hc + hcol)) * Sc + s) * HDc;
                        Qh[rowb + d]      = (unsigned short)f2bf(y0 * QSC);
                        Qh[rowb + d + 32] = (unsigned short)f2bf(y1 * QSC);
                    } else {
                        int T = s >> 6, tok = s & 63;
                        size_t tb = (((size_t)(bbk * Hc + hcol)) * 32 + T) * 8;
                        size_t off0 = ((tb + (d >> 3)) * 64 + tok) * 8 + (d & 7);
                        size_t off1 = ((tb + (d >> 3) + 4) * 64 + tok) * 8 + (d & 7);
                        Kh[off0] = (unsigned short)f2bf(y0);
                        Kh[off1] = (unsigned short)f2bf(y1);
                    }
                }
            }
    }
}

// ---------------------------------------------------------------------------
// MFMA flash attention v11: attn10 with the band dimension removed.
// 128 q/block, 8 waves x 16 q each -> grid 512 = 2 blocks/CU = 4 waves/SIMD
// (vs attn10's 2): doubled TLP covers the serial QK->exp->PV latency chain.
// Staging map, triple-buffer, counted vmcnt(2) + raw s_barrier, XCD
// clustering, P-transpose, epilogue formulas all unchanged.
// ---------------------------------------------------------------------------
__global__ __launch_bounds__(512) void attn11(
    const unsigned short* __restrict__ Qh,
    const unsigned short* __restrict__ Kh,
    const unsigned short* __restrict__ Vh,
    unsigned short* __restrict__ AOh, unsigned short* __restrict__ AOl) {
    __shared__ __align__(16) unsigned short KsH[3 * 4096], VtH[3 * 4096];

    const int t = threadIdx.x;
    const int lane = t & 63;
    const int wave = t >> 6;               // 0..7 (= q-band)
    const int l = lane & 15;
    const int quad = lane >> 4;
    const int id = blockIdx.x;             // 0..511
    const int bh = (id & 7) * 4 + (id >> 7);   // XCD-clustered (4 bh / XCD slot)
    const int qt = (id >> 3) & 15;
    const int q0 = qt * 128;
    const int b = bh >> 4;
    const int hh = bh & 15;

    const bf16x8 ONES8 = {(short)0x3F80, (short)0x3F80, (short)0x3F80, (short)0x3F80,
                          (short)0x3F80, (short)0x3F80, (short)0x3F80, (short)0x3F80};

    // Q fragments (B operand: n=q=lane&15, k=d=quad*8+j); rows q0+wave*16+l
    bf16x8 qf[2];
    {
        size_t rowb = ((size_t)bh * Sc + q0 + wave * 16 + l) * HDc;
#pragma unroll
        for (int ks = 0; ks < 2; ks++)
            qf[ks] = *(const bf16x8*)(Qh + rowb + ks * 32 + quad * 8);
    }

    f32x4 o[4], lac;
    lac = (f32x4){0.f, 0.f, 0.f, 0.f};
#pragma unroll
    for (int i = 0; i < 4; i++) o[i] = (f32x4){0.f, 0.f, 0.f, 0.f};

    // staging: 16 chunks of 512 elems per kt (K: 0-7, V: 8-15); wave w owns
    // chunks w*2, w*2+1 (waves 0-3 -> K, waves 4-7 -> V). LDS dst uniform.
    const int tensor = wave >> 2;          // 0 = K, 1 = V
    const int coff0 = (wave * 2) & 7;      // 0,2,4,6
    unsigned short* larr = tensor ? VtH : KsH;
    const unsigned short* gT =
        (tensor ? Vh : Kh) + (size_t)bh * Sc * HDc + coff0 * 512 + lane * 8;

    // prologue: kt=0 into buffer 0
#pragma unroll
    for (int q = 0; q < 2; q++)
        __builtin_amdgcn_global_load_lds(
            (gp_t)(gT + q * 512),
            (lp_t)(larr + coff0 * 512 + q * 512),
            16, 0, 0);

    int bc = 0;   // kt % 3
    for (int kt = 0; kt < 32; kt++) {
        if (kt + 1 < 32) {
            int nb = bc + 1; if (nb == 3) nb = 0;     // (kt+1) % 3
            const unsigned short* g = gT + (size_t)(kt + 1) * 4096;
            unsigned short* dst = larr + nb * 4096 + coff0 * 512;
#pragma unroll
            for (int q = 0; q < 2; q++)
                __builtin_amdgcn_global_load_lds(
                    (gp_t)(g + q * 512),
                    (lp_t)(dst + q * 512),
                    16, 0, 0);
            asm volatile("s_waitcnt vmcnt(2)" ::: "memory");   // own kt-loads landed
        } else {
            asm volatile("s_waitcnt vmcnt(0)" ::: "memory");
        }
        __builtin_amdgcn_s_barrier();                          // all waves' kt-loads landed
        const unsigned short* Kbuf = KsH + bc * 4096;
        const unsigned short* Vbuf = VtH + bc * 4096;

        // ---- S^T = K @ Q^T: A=K frag (m=tok), B=Q frag (n=q) ----
        f32x4 s[4];
#pragma unroll
        for (int tt = 0; tt < 4; tt++) s[tt] = (f32x4){0.f, 0.f, 0.f, 0.f};
        __builtin_amdgcn_s_setprio(1);
#pragma unroll
        for (int ks = 0; ks < 2; ks++)
#pragma unroll
            for (int tt = 0; tt < 4; tt++) {
                bf16x8 kf = *(const bf16x8*)&Kbuf[((ks * 4 + quad) * 64 + tt * 16 + l) * 8];
                s[tt] = __builtin_amdgcn_mfma_f32_16x16x32_bf16(kf, qf[ks], s[tt], 0, 0, 0);
            }
        __builtin_amdgcn_s_setprio(0);

        // ---- P^T = exp2(S^T), packed + permlane-transposed into K=32
        //      B-operand fragments (tokens quad*8+j contiguous per lane) ----
        bf16x8 pf[2];
#pragma unroll
        for (int ttp = 0; ttp < 2; ttp++) {
            unsigned A0, A1, B0, B1;
            exppack(s[2 * ttp], A0, A1);       // tokens ttp*32 + quad*4 + {0..3}
            exppack(s[2 * ttp + 1], B0, B1);   // tokens ttp*32 + 16 + quad*4 + {0..3}
            plswap32(A0, B0);
            plswap16(A0, B0);   // A0 -> frag word0, B0 -> frag word2
            plswap32(A1, B1);
            plswap16(A1, B1);   // A1 -> frag word1, B1 -> frag word3
            u32x4 fw = {A0, A1, B0, B1};
            bf16x8 p8 = __builtin_bit_cast(bf16x8, fw);
            pf[ttp] = p8;
            lac = __builtin_amdgcn_mfma_f32_16x16x32_bf16(ONES8, p8, lac, 0, 0, 0);
        }

        // ---- O^T += V^T @ P^T (K=32) ----
        __builtin_amdgcn_s_setprio(1);
#pragma unroll
        for (int kk = 0; kk < 2; kk++)
#pragma unroll
            for (int dd = 0; dd < 4; dd++) {
                bf16x8 vf = *(const bf16x8*)
                    &Vbuf[(size_t)((kk * 4 + quad) * 64 + dd * 16 + l) * 8];
                o[dd] = __builtin_amdgcn_mfma_f32_16x16x32_bf16(vf, pf[kk], o[dd], 0, 0, 0);
            }
        __builtin_amdgcn_s_setprio(0);
        if (++bc == 3) bc = 0;
    }

    // ---- epilogue: O^T frag: col q = lane&15, row d = dd*16 + quad*4 + r ----
    {
        float inv = 1.f / lac[0];   // all 4 regs equal (ONES-A rows identical)
        int q = q0 + wave * 16 + l;
        size_t rowb = ((size_t)b * Sc + q) * Dc + hh * HDc + quad * 4;
#pragma unroll
        for (int dd = 0; dd < 4; dd++) {
            us4 h4, l4;
#pragma unroll
            for (int r = 0; r < 4; r++)
                split2(o[dd][r] * inv,
                       ((unsigned short*)&h4)[r], ((unsigned short*)&l4)[r]);
            *(us4*)(AOh + rowb + dd * 16) = h4;
            *(us4*)(AOl + rowb + dd * 16) = l4;
        }
    }
}

// ---------------------------------------------------------------------------
// Output projection GEMM v9 (split-bf16 3-product, dbuf, split-K=2 partials):
// COALESCED staging (round-10 proven). UNTOUCHED.
// ---------------------------------------------------------------------------
__global__ __launch_bounds__(512, 4) void gemm_out9(
    const unsigned short* __restrict__ Ah, const unsigned short* __restrict__ Al,
    const unsigned short* __restrict__ Wh, const unsigned short* __restrict__ Wl,
    float* __restrict__ C0, float* __restrict__ C1) {
    constexpr int K = 1024;
    // [buf][row 128][chunk 4][8 shorts] = 8 KB per tensor per buf
    __shared__ __align__(16) unsigned short AsH[2][4096], AsL[2][4096],
                                            BsH[2][4096], BsL[2][4096];

    const int t = threadIdx.x;
    const int lane = t & 63;
    const int wave = t >> 6;               // 0..7
    const int l15 = lane & 15;
    const int quad = lane >> 4;
    const int wr = wave >> 1;              // 0..3
    const int wc = wave & 1;               // 0..1
    const int m0 = blockIdx.x * 128;   // m fastest -> XCD A-locality
    const int n0 = blockIdx.y * 128;
    const int k0 = blockIdx.z * 512;   // split-K half
    float* __restrict__ C = blockIdx.z ? C1 : C0;

    // staging: chunk c = t; row = c>>2, slot = c&3, global chunk = slot^(row&3)
    const int rr = t >> 2, ss = t & 3;
    const int gc = (ss ^ (rr & 3)) * 8;
    const unsigned short* gah = Ah + (size_t)(m0 + rr) * K + k0 + gc;
    const unsigned short* gal = Al + (size_t)(m0 + rr) * K + k0 + gc;
    const unsigned short* gbh = Wh + (size_t)(n0 + rr) * K + k0 + gc;
    const unsigned short* gbl = Wl + (size_t)(n0 + rr) * K + k0 + gc;
    const int dd_ = t * 8;                 // linear LDS dst (shorts)

    f32x4 acc[2][4];
#pragma unroll
    for (int i = 0; i < 2; i++)
#pragma unroll
        for (int j = 0; j < 4; j++) acc[i][j] = (f32x4){0.f, 0.f, 0.f, 0.f};

#define STGO(X) do {                                                                       \
        const int _ko = (X) * 32;                                                          \
        const int _bf = (X) & 1;                                                           \
        __builtin_amdgcn_global_load_lds((gp_t)(gah + _ko), (lp_t)(&AsH[_bf][dd_]), 16, 0, 0); \
        __builtin_amdgcn_global_load_lds((gp_t)(gal + _ko), (lp_t)(&AsL[_bf][dd_]), 16, 0, 0); \
        __builtin_amdgcn_global_load_lds((gp_t)(gbh + _ko), (lp_t)(&BsH[_bf][dd_]), 16, 0, 0); \
        __builtin_amdgcn_global_load_lds((gp_t)(gbl + _ko), (lp_t)(&BsL[_bf][dd_]), 16, 0, 0); \
    } while (0)

    STGO(0);

    for (int it = 0; it < 16; ++it) {
        __syncthreads();
        if (it + 1 < 16) STGO(it + 1);
        const int bf = it & 1;
        bf16x8 ah[2], al[2], bh[4], bl[4];
#pragma unroll
        for (int i = 0; i < 2; i++) {
            int row = wr * 32 + i * 16 + l15;
            int ra = row * 32 + (quad ^ (row & 3)) * 8;
            ah[i] = *(const bf16x8*)&AsH[bf][ra];
            al[i] = *(const bf16x8*)&AsL[bf][ra];
        }
#pragma unroll
        for (int j = 0; j < 4; j++) {
            int row = wc * 64 + j * 16 + l15;
            int rb = row * 32 + (quad ^ (row & 3)) * 8;
            bh[j] = *(const bf16x8*)&BsH[bf][rb];
            bl[j] = *(const bf16x8*)&BsL[bf][rb];
        }
#pragma unroll
        for (int i = 0; i < 2; i++)
#pragma unroll
            for (int j = 0; j < 4; j++) {
                acc[i][j] = __builtin_amdgcn_mfma_f32_16x16x32_bf16(ah[i], bh[j], acc[i][j], 0, 0, 0);
                acc[i][j] = __builtin_amdgcn_mfma_f32_16x16x32_bf16(al[i], bh[j], acc[i][j], 0, 0, 0);
                acc[i][j] = __builtin_amdgcn_mfma_f32_16x16x32_bf16(ah[i], bl[j], acc[i][j], 0, 0, 0);
            }
    }
#undef STGO

#pragma unroll
    for (int i = 0; i < 2; i++)
#pragma unroll
        for (int j = 0; j < 4; j++)
#pragma unroll
            for (int r = 0; r < 4; r++) {
                int m = m0 + wr * 32 + i * 16 + quad * 4 + r;
                int n = n0 + wc * 64 + j * 16 + l15;
                C[(size_t)m * Dc + n] = acc[i][j][r];
            }
}

// ---------------------------------------------------------------------------
// Split-K combine: out += P1 (float4 vectorized).
// ---------------------------------------------------------------------------
__global__ void add_partial(float* __restrict__ out, const float* __restrict__ p1) {
    int i = (blockIdx.x * 256 + threadIdx.x) * 4;
    float4 a = *(const float4*)(out + i);
    float4 b = *(const float4*)(p1 + i);
    a.x += b.x; a.y += b.y; a.z += b.z; a.w += b.w;
    *(float4*)(out + i) = a;
}

// ---------------------------------------------------------------------------
extern "C" void kernel_launch(void* const* d_in, const int* in_sizes, int n_in,
                              void* d_out, int out_size, void* d_ws, size_t ws_size,
                              hipStream_t stream) {
    const float* x  = (const float*)d_in[0];
    const float* Wq = (const float*)d_in[1];
    const float* Wk = (const float*)d_in[2];
    const float* Wv = (const float*)d_in[3];
    const float* Wo = (const float*)d_in[4];
    float* out = (float*)d_out;

    unsigned short* usw = (unsigned short*)d_ws;
    const size_t M4 = (size_t)1 << 22;   // 4M elements
    unsigned short* whAll = usw;                 // 4 x 1M weights hi
    unsigned short* wlAll = usw + M4;            // lo (only Wo slot used)
    unsigned short* xh = usw + 2 * M4;           // x hi (later AOh)
    unsigned short* xl = usw + 3 * M4;           // later AOl
    unsigned short* Qh = usw + 4 * M4;
    unsigned short* Kh = usw + 5 * M4;
    unsigned short* Vh = usw + 6 * M4;
    float* ct = (float*)(usw + 7 * M4);
    float* st_ = ct + (size_t)Sc * 32;
    unsigned short* AOh = xh;   // x dead after QKV GEMM
    unsigned short* AOl = xl;
    // split-K partial: 16 MB fp32 reusing Qh+Kh slots (dead after attn)
    float* P1 = (float*)Qh;

    // 1. RoPE table
    rope_table<<<dim3((Sc * 32) / 256), dim3(256), 0, stream>>>(ct, st_);
    // 2. convert x + weights to bf16 (Wo keeps hi/lo)
    split_xw<<<dim3(4096, 5), dim3(256), 0, stream>>>(x, Wq, Wk, Wv, Wo, xh, whAll, wlAll);
    // 3. QKV projections: coalesced BK=64 staging + XOR swizzle, fused epilogues
    gemm_qkv9<<<dim3(32, 8, 3), dim3(512), 0, stream>>>(
        xh, whAll, Qh, Kh, Vh, ct, st_);
    // 4. attention: 128q/block, 8 waves x 16q, 2 blocks/CU (4 waves/SIMD)
    attn11<<<dim3(512), dim3(512), 0, stream>>>(Qh, Kh, Vh, AOh, AOl);
    // 5. output projection: coalesced staging, split-K=2 partials
    gemm_out9<<<dim3(32, 8, 2), dim3(512), 0, stream>>>(
        AOh, AOl, whAll + 3 * (1 << 20), wlAll + 3 * (1 << 20), out, P1);
    // 6. combine partials
    add_partial<<<dim3(4096), dim3(256), 0, stream>>>(out, P1);
}